// Round 8
// baseline (1366.481 us; speedup 1.0000x reference)
//
#include <hip/hip_runtime.h>
#include <stdint.h>

// JTMPN on MI355X — round 15: gather occupancy probe (discriminator).
// r14: gather unchanged at 148us/10.8 B/cy/CU, Occ 62% (20 waves/CU), VGPR 36,
// no LDS -> residency capped by workgroup slots, not resources. If the gather
// is latency-bound, waves are the only lever: 1024-thread blocks +
// __launch_bounds__(1024,8) -> 32 waves/CU (+60% outstanding misses).
// If null, 10.8 B/cy/CU is a hard per-CU request-path wall (declare and move
// to GEMM structure next). Same per-wave code, bit-identical numerics, same
// XCD-affine mapping. GEMMs = r14 dbuf (verified 1221us) verbatim.

#define MAX_NB 15
#define HID 512
#define NA 32768
#define NB 65536
#define NMESS 8192

typedef unsigned short u16;
typedef unsigned int u32;
typedef __bf16 bf16x8 __attribute__((ext_vector_type(8)));
typedef float f32x4 __attribute__((ext_vector_type(4)));

__device__ __forceinline__ u16 f2bf(float f) {
  u32 u = __builtin_bit_cast(u32, f);
  u32 r = (u + 0x7fffu + ((u >> 16) & 1u)) >> 16;
  return (u16)r;
}
__device__ __forceinline__ float bflo(u32 u) {
  return __builtin_bit_cast(float, u << 16);
}
__device__ __forceinline__ float bfhi(u32 u) {
  return __builtin_bit_cast(float, u & 0xffff0000u);
}

__device__ __forceinline__ void async16(const u16* g, u16* l) {
  __builtin_amdgcn_global_load_lds(
      (const __attribute__((address_space(1))) u32*)g,
      (__attribute__((address_space(3))) u32*)l, 16, 0, 0);
}

// ---------------- prep: fp32 -> bf16 conversions / transposes ----------------
__global__ __launch_bounds__(256) void prep_kernel(
    const float* __restrict__ fbonds, const float* __restrict__ tree,
    const float* __restrict__ Wi, const float* __restrict__ Wh,
    const float* __restrict__ Wo, u16* __restrict__ msg,
    u16* __restrict__ fbpad, u16* __restrict__ wcat, u16* __restrict__ wo_t) {
  int t = blockIdx.x * 256 + threadIdx.x;
  const int N0 = NMESS * HID;  // 4194304
  const int N1 = NB * 64;      // 4194304
  const int N2 = 512 * 576;    // 294912
  const int N3 = 512 * 576;    // 294912
  if (t < N0) { msg[t] = f2bf(tree[t]); return; }
  t -= N0;
  if (t < N1) {
    int row = t >> 6, c = t & 63;
    fbpad[t] = (c < 40) ? f2bf(fbonds[row * 40 + c]) : (u16)0;
    return;
  }
  t -= N1;
  if (t < N2) {
    int n = t / 576, k = t - n * 576;
    float v = 0.f;
    if (k < 40) v = Wi[k * 512 + n];
    else if (k >= 64) v = Wh[(k - 64) * 512 + n];
    wcat[t] = f2bf(v);
    return;
  }
  t -= N2;
  if (t < N3) {
    int n = t / 576, k = t - n * 576;
    float v = 0.f;
    if (k < 512) v = Wo[(35 + k) * 512 + n];        // nei part
    else if (k < 547) v = Wo[(k - 512) * 512 + n];  // fatoms part
    wo_t[t] = f2bf(v);
    return;
  }
}

// ---------------- gather-sum: wave per row, 16 waves/block ----------------
// 1024-thread blocks, __launch_bounds__(1024,8) -> 2 blocks/CU = 32 waves/CU.
// Per-wave body identical to r14 (j-ascending summation, bit-identical).
__global__ __launch_bounds__(1024, 8) void gather_bonds(
    const u16* __restrict__ msg, const int* __restrict__ bgraph,
    u16* __restrict__ nei) {
  const int xcd = blockIdx.x & 7;
  const int chunk = blockIdx.x >> 3;
  int row = xcd * (NB / 8) + chunk * 16 + (threadIdx.x >> 6);
  int lane = threadIdx.x & 63;
  const int* idxp = bgraph + row * MAX_NB;
  int ids[MAX_NB];
#pragma unroll
  for (int j = 0; j < MAX_NB; j++) ids[j] = __builtin_nontemporal_load(idxp + j);
  uint4 v[MAX_NB];
#pragma unroll
  for (int j = 0; j < MAX_NB; j++)
    v[j] = *(const uint4*)(msg + (size_t)ids[j] * HID + lane * 8);
  float acc[8] = {0, 0, 0, 0, 0, 0, 0, 0};
#pragma unroll
  for (int j = 0; j < MAX_NB; j++) {
    acc[0] += bflo(v[j].x); acc[1] += bfhi(v[j].x);
    acc[2] += bflo(v[j].y); acc[3] += bfhi(v[j].y);
    acc[4] += bflo(v[j].z); acc[5] += bfhi(v[j].z);
    acc[6] += bflo(v[j].w); acc[7] += bfhi(v[j].w);
  }
  uint4 o;
  o.x = (u32)f2bf(acc[0]) | ((u32)f2bf(acc[1]) << 16);
  o.y = (u32)f2bf(acc[2]) | ((u32)f2bf(acc[3]) << 16);
  o.z = (u32)f2bf(acc[4]) | ((u32)f2bf(acc[5]) << 16);
  o.w = (u32)f2bf(acc[6]) | ((u32)f2bf(acc[7]) << 16);
  *(uint4*)(nei + (size_t)row * HID + lane * 8) = o;
}

// atom gather: same structure; builds ainput [nei(512) | fatoms(35) | pad(29)]
__global__ __launch_bounds__(1024, 8) void gather_atoms(
    const u16* __restrict__ msg, const int* __restrict__ agraph,
    const float* __restrict__ fatoms, u16* __restrict__ ainput) {
  const int xcd = blockIdx.x & 7;
  const int chunk = blockIdx.x >> 3;
  int row = xcd * (NA / 8) + chunk * 16 + (threadIdx.x >> 6);
  int lane = threadIdx.x & 63;
  const int* idxp = agraph + row * MAX_NB;
  int ids[MAX_NB];
#pragma unroll
  for (int j = 0; j < MAX_NB; j++) ids[j] = __builtin_nontemporal_load(idxp + j);
  uint4 v[MAX_NB];
#pragma unroll
  for (int j = 0; j < MAX_NB; j++)
    v[j] = *(const uint4*)(msg + (size_t)ids[j] * HID + lane * 8);
  float acc[8] = {0, 0, 0, 0, 0, 0, 0, 0};
#pragma unroll
  for (int j = 0; j < MAX_NB; j++) {
    acc[0] += bflo(v[j].x); acc[1] += bfhi(v[j].x);
    acc[2] += bflo(v[j].y); acc[3] += bfhi(v[j].y);
    acc[4] += bflo(v[j].z); acc[5] += bfhi(v[j].z);
    acc[6] += bflo(v[j].w); acc[7] += bfhi(v[j].w);
  }
  uint4 o;
  o.x = (u32)f2bf(acc[0]) | ((u32)f2bf(acc[1]) << 16);
  o.y = (u32)f2bf(acc[2]) | ((u32)f2bf(acc[3]) << 16);
  o.z = (u32)f2bf(acc[4]) | ((u32)f2bf(acc[5]) << 16);
  o.w = (u32)f2bf(acc[6]) | ((u32)f2bf(acc[7]) << 16);
  u16* arow = ainput + (size_t)row * 576;
  *(uint4*)(arow + lane * 8) = o;
  float tv = (lane < 35) ? fatoms[(size_t)row * 35 + lane] : 0.f;
  arow[512 + lane] = f2bf(tv);
}

// ---------------- 128x128 bf16 MFMA GEMM, dbuf prefetch, XCD-swizzled -------
// r14-verified verbatim. One barrier per k-step; A split at kSplit.
template <int EPI>
__global__ __launch_bounds__(256) void gemm_k(
    const u16* __restrict__ A1, int s1, int kSplit,
    const u16* __restrict__ A2, const u16* __restrict__ Bt, int Bstride, int K,
    int mtx, u16* __restrict__ msgout, const float* __restrict__ bo,
    const int* __restrict__ scope, float* __restrict__ out) {
  __shared__ __align__(16) u16 As[2][128 * 32];
  __shared__ __align__(16) u16 Bs[2][128 * 32];
  const int L = blockIdx.x;
  const int xcd = L & 7;
  const int q = L >> 3;
  const int mBase = (xcd * mtx + (q >> 2)) * 128;
  const int nBase = (q & 3) * 128;
  const int t = threadIdx.x;
  const int lane = t & 63;
  const int w = t >> 6;
  const int wm = w & 1, wn = w >> 1;
  const int r = t >> 2;
  const int c8 = (t & 3) * 8;
  const int q8 = (lane >> 4) * 8;
  const int l15 = lane & 15;

  f32x4 acc[4][4];
#pragma unroll
  for (int i = 0; i < 4; i++)
#pragma unroll
    for (int j = 0; j < 4; j++)
#pragma unroll
      for (int rg = 0; rg < 4; rg++) acc[i][j][rg] = 0.f;

  auto stage = [&](int c, int kb) {
    const u16* Ab;
    int Astr, kOff;
    if (kb < kSplit) { Ab = A1; Astr = s1; kOff = kb; }
    else { Ab = A2; Astr = 512; kOff = kb - kSplit; }
    async16(Ab + (size_t)(mBase + r) * Astr + kOff + c8, As[c] + r * 32 + c8);
    async16(Ab + (size_t)(mBase + r + 64) * Astr + kOff + c8,
            As[c] + (r + 64) * 32 + c8);
    async16(Bt + (size_t)(nBase + r) * Bstride + kb + c8, Bs[c] + r * 32 + c8);
    async16(Bt + (size_t)(nBase + r + 64) * Bstride + kb + c8,
            Bs[c] + (r + 64) * 32 + c8);
  };

  stage(0, 0);
  __syncthreads();  // drains vmcnt: buf0 ready
  int cur = 0;
  for (int kb = 0; kb < K; kb += 32) {
    if (kb + 32 < K) stage(cur ^ 1, kb + 32);  // prefetch next tile
    bf16x8 av[4], bv[4];
#pragma unroll
    for (int i = 0; i < 4; i++)
      av[i] = *(const bf16x8*)(As[cur] + (wm * 64 + i * 16 + l15) * 32 + q8);
#pragma unroll
    for (int j = 0; j < 4; j++)
      bv[j] = *(const bf16x8*)(Bs[cur] + (wn * 64 + j * 16 + l15) * 32 + q8);
#pragma unroll
    for (int i = 0; i < 4; i++)
#pragma unroll
      for (int j = 0; j < 4; j++)
        acc[i][j] = __builtin_amdgcn_mfma_f32_16x16x32_bf16(av[i], bv[j],
                                                            acc[i][j], 0, 0, 0);
    __syncthreads();  // all reads of buf[cur] done + next buf staged
    cur ^= 1;
  }

  if (EPI == 2) {
#pragma unroll
    for (int m = 0; m < 2; m++) {
      int mol = (mBase + wm * 64 + m * 32) >> 5;
      float inv_le = 1.0f / (float)scope[mol * 2 + 1];
#pragma unroll
      for (int j = 0; j < 4; j++) {
        int col = nBase + wn * 64 + j * 16 + l15;
        float bias = bo[col];
        float s = 0.f;
#pragma unroll
        for (int i = 2 * m; i < 2 * m + 2; i++)
#pragma unroll
          for (int rg = 0; rg < 4; rg++)
            s += fmaxf(acc[i][j][rg] + bias, 0.f);
        s += __shfl_xor(s, 16, 64);
        s += __shfl_xor(s, 32, 64);
        if (lane < 16) out[(size_t)mol * HID + col] = s * inv_le;
      }
    }
  } else {
#pragma unroll
    for (int i = 0; i < 4; i++) {
      int row = mBase + wm * 64 + i * 16 + (lane >> 4) * 4;
#pragma unroll
      for (int j = 0; j < 4; j++) {
        int col = nBase + wn * 64 + j * 16 + l15;
#pragma unroll
        for (int rg = 0; rg < 4; rg++) {
          size_t gi = (size_t)(row + rg) * HID + col;
          msgout[(size_t)NMESS * HID + gi] = f2bf(fmaxf(acc[i][j][rg], 0.f));
        }
      }
    }
  }
}

// ---------------- launch ----------------
extern "C" void kernel_launch(void* const* d_in, const int* in_sizes, int n_in,
                              void* d_out, int out_size, void* d_ws,
                              size_t ws_size, hipStream_t stream) {
  const float* fatoms = (const float*)d_in[0];
  const float* fbonds = (const float*)d_in[1];
  const int* agraph = (const int*)d_in[2];
  const int* bgraph = (const int*)d_in[3];
  const int* scope = (const int*)d_in[4];
  const float* tree = (const float*)d_in[5];
  const float* Wi = (const float*)d_in[6];
  const float* Wh = (const float*)d_in[7];
  const float* Wo = (const float*)d_in[8];
  const float* bo = (const float*)d_in[9];
  float* out = (float*)d_out;

  // layout (152.2 MB, = r10/r14 verbatim):
  // [msg 75.5MB][nei 67MB][fbpad 8.4MB][wcat 0.59MB][wo_t 0.59MB]
  char* ws = (char*)d_ws;
  u16* msg = (u16*)(ws);
  u16* nei = (u16*)(ws + 75497472ull);
  u16* fbpad = (u16*)(ws + 142606336ull);
  u16* wcat = (u16*)(ws + 150994944ull);
  u16* wo_t = (u16*)(ws + 151584768ull);
  u16* ainput = nei;  // alias: nei dead once gather_atoms runs

  prep_kernel<<<35072, 256, 0, stream>>>(fbonds, tree, Wi, Wh, Wo, msg, fbpad,
                                         wcat, wo_t);

  // init: msg_graph = relu(fbpad @ Wi)  (K=64, first 64 k-cols of wcat)
  gemm_k<0><<<2048, 256, 0, stream>>>(fbpad, 64, 64, nullptr, wcat, 576, 64,
                                      64, msg, nullptr, nullptr, nullptr);
  for (int d = 0; d < 5; d++) {
    gather_bonds<<<NB / 16, 1024, 0, stream>>>(msg, bgraph, nei);
    // msg_graph = relu([fbpad | nei] @ wcat), K=576
    gemm_k<0><<<2048, 256, 0, stream>>>(fbpad, 64, 64, nei, wcat, 576, 576,
                                        64, msg, nullptr, nullptr, nullptr);
  }
  gather_atoms<<<NA / 16, 1024, 0, stream>>>(msg, agraph, fatoms, ainput);
  // out: mean over molecule of relu(ainput @ Wo + bo), K=576
  gemm_k<2><<<1024, 256, 0, stream>>>(ainput, 576, 576, nullptr, wo_t, 576,
                                      576, 32, nullptr, bo, scope, out);
}

// Round 9
// 1230.821 us; speedup vs baseline: 1.1102x; 1.1102x over previous
//
#include <hip/hip_runtime.h>
#include <stdint.h>

// JTMPN on MI355X — round 16: hazard-free overlap via role-split launches.
// Gather: wall confirmed (latency x ~64 MSHR/CU; occupancy/ILP levers null)
// -> r7 form restored. GEMM (~330us serial) hidden under the gather with a
// 3-launch pipeline per iteration:
//   L1 pure gather chunks[0,45)        (rows for L2's gemm)
//   L2 MIXED: gemm tiles[0,45) (reads L1 rows) || gather chunks[45,64)
//   L3 pure gemm tiles[45,64)
// Blocks never wait (roles fixed by blockIdx; all deps satisfied by stream
// order) -> deadlock-impossible; worst case = serial. msg WAR in L2 solved by
// graph ping-pong (tree shared). 216.1MB layout behind runtime ws_size check;
// r14-class serial fallback (1221us) otherwise. Numerics bit-identical.

#define MAX_NB 15
#define HID 512
#define NA 32768
#define NB 65536
#define NMESS 8192
#define GAPE 33554432u  // one graph buffer, elements

typedef unsigned short u16;
typedef unsigned int u32;
typedef __bf16 bf16x8 __attribute__((ext_vector_type(8)));
typedef float f32x4 __attribute__((ext_vector_type(4)));

__device__ __forceinline__ u16 f2bf(float f) {
  u32 u = __builtin_bit_cast(u32, f);
  u32 r = (u + 0x7fffu + ((u >> 16) & 1u)) >> 16;
  return (u16)r;
}
__device__ __forceinline__ float bflo(u32 u) {
  return __builtin_bit_cast(float, u << 16);
}
__device__ __forceinline__ float bfhi(u32 u) {
  return __builtin_bit_cast(float, u & 0xffff0000u);
}

__device__ __forceinline__ void async16(const u16* g, u16* l) {
  __builtin_amdgcn_global_load_lds(
      (const __attribute__((address_space(1))) u32*)g,
      (__attribute__((address_space(3))) u32*)l, 16, 0, 0);
}

// ---------------- prep ----------------
__global__ __launch_bounds__(256) void prep_kernel(
    const float* __restrict__ fbonds, const float* __restrict__ tree,
    const float* __restrict__ Wi, const float* __restrict__ Wh,
    const float* __restrict__ Wo, u16* __restrict__ tab,
    u16* __restrict__ fbc, u16* __restrict__ wcat, u16* __restrict__ wo_t) {
  int t = blockIdx.x * 256 + threadIdx.x;
  const int N0 = NMESS * HID;
  if (t < N0) { tab[t] = f2bf(tree[t]); return; }
  t -= N0;
  const int N1 = NB * 40;  // fbonds bf16, natural stride 40, +32 zero slack
  if (t < N1 + 32) { fbc[t] = (t < N1) ? f2bf(fbonds[t]) : (u16)0; return; }
  t -= N1 + 32;
  if (t < 576 * 512) {  // wcat[n][k]: k<40 Wi, 40..63 zero, >=64 Wh
    int n = t / 576, k = t - n * 576;
    float v = 0.f;
    if (k < 40) v = Wi[k * 512 + n];
    else if (k >= 64) v = Wh[(k - 64) * 512 + n];
    wcat[t] = f2bf(v);
    return;
  }
  t -= 576 * 512;
  if (t < 576 * 512) {  // wo_t[n][k]: k<512 nei, 512..546 fatoms
    int n = t / 576, k = t - n * 576;
    float v = 0.f;
    if (k < 512) v = Wo[(35 + k) * 512 + n];
    else if (k < 547) v = Wo[(k - 512) * 512 + n];
    wo_t[t] = f2bf(v);
    return;
  }
}

// ---------------- pure gathers (r7-verified body; parity read offset) -------
__global__ __launch_bounds__(256) void gather_bonds(
    const u16* __restrict__ tab, const int* __restrict__ bgraph,
    u16* __restrict__ nei, u32 pOff) {
  const int xcd = blockIdx.x & 7;
  const int chunk = blockIdx.x >> 3;
  int row = xcd * (NB / 8) + chunk * 4 + (threadIdx.x >> 6);
  int lane = threadIdx.x & 63;
  const int* idxp = bgraph + row * MAX_NB;
  float acc[8] = {0, 0, 0, 0, 0, 0, 0, 0};
#pragma unroll
  for (int j = 0; j < MAX_NB; j++) {
    int id = idxp[j];
    u32 off = (u32)id * HID + (id >= NMESS ? pOff : 0u);
    uint4 v = *(const uint4*)(tab + (size_t)off + lane * 8);
    acc[0] += bflo(v.x); acc[1] += bfhi(v.x);
    acc[2] += bflo(v.y); acc[3] += bfhi(v.y);
    acc[4] += bflo(v.z); acc[5] += bfhi(v.z);
    acc[6] += bflo(v.w); acc[7] += bfhi(v.w);
  }
  uint4 o;
  o.x = (u32)f2bf(acc[0]) | ((u32)f2bf(acc[1]) << 16);
  o.y = (u32)f2bf(acc[2]) | ((u32)f2bf(acc[3]) << 16);
  o.z = (u32)f2bf(acc[4]) | ((u32)f2bf(acc[5]) << 16);
  o.w = (u32)f2bf(acc[6]) | ((u32)f2bf(acc[7]) << 16);
  *(uint4*)(nei + (size_t)row * HID + lane * 8) = o;
}

__global__ __launch_bounds__(256) void gather_atoms(
    const u16* __restrict__ tab, const int* __restrict__ agraph,
    const float* __restrict__ fatoms, u16* __restrict__ ainput, u32 pOff) {
  const int xcd = blockIdx.x & 7;
  const int chunk = blockIdx.x >> 3;
  int row = xcd * (NA / 8) + chunk * 4 + (threadIdx.x >> 6);
  int lane = threadIdx.x & 63;
  const int* idxp = agraph + row * MAX_NB;
  float acc[8] = {0, 0, 0, 0, 0, 0, 0, 0};
#pragma unroll
  for (int j = 0; j < MAX_NB; j++) {
    int id = idxp[j];
    u32 off = (u32)id * HID + (id >= NMESS ? pOff : 0u);
    uint4 v = *(const uint4*)(tab + (size_t)off + lane * 8);
    acc[0] += bflo(v.x); acc[1] += bfhi(v.x);
    acc[2] += bflo(v.y); acc[3] += bfhi(v.y);
    acc[4] += bflo(v.z); acc[5] += bfhi(v.z);
    acc[6] += bflo(v.w); acc[7] += bfhi(v.w);
  }
  uint4 o;
  o.x = (u32)f2bf(acc[0]) | ((u32)f2bf(acc[1]) << 16);
  o.y = (u32)f2bf(acc[2]) | ((u32)f2bf(acc[3]) << 16);
  o.z = (u32)f2bf(acc[4]) | ((u32)f2bf(acc[5]) << 16);
  o.w = (u32)f2bf(acc[6]) | ((u32)f2bf(acc[7]) << 16);
  u16* arow = ainput + (size_t)row * 576;
  *(uint4*)(arow + lane * 8) = o;
  float tv = (lane < 35) ? fatoms[(size_t)row * 35 + lane] : 0.f;
  arow[512 + lane] = f2bf(tv);
}

// ---------------- pure GEMM, 256 threads, r14 dbuf, +tileStart --------------
template <int EPI>
__global__ __launch_bounds__(256) void gemm_k(
    const u16* __restrict__ A1, int s1, int kSplit,
    const u16* __restrict__ A2, const u16* __restrict__ Bt, int K, int mtx,
    int tileStart, u16* __restrict__ gw, const float* __restrict__ bo,
    const int* __restrict__ scope, float* __restrict__ out) {
  __shared__ __align__(16) u16 As[2][128 * 32];
  __shared__ __align__(16) u16 Bs[2][128 * 32];
  const int L = blockIdx.x;
  const int xcd = L & 7;
  const int q = L >> 3;
  const int mBase = (xcd * mtx + tileStart + (q >> 2)) * 128;
  const int nBase = (q & 3) * 128;
  const int t = threadIdx.x;
  const int lane = t & 63;
  const int w = t >> 6;
  const int wm = w & 1, wn = w >> 1;
  const int r = t >> 2;
  const int c8 = (t & 3) * 8;
  const int q8 = (lane >> 4) * 8;
  const int l15 = lane & 15;

  f32x4 acc[4][4];
#pragma unroll
  for (int i = 0; i < 4; i++)
#pragma unroll
    for (int j = 0; j < 4; j++)
#pragma unroll
      for (int rg = 0; rg < 4; rg++) acc[i][j][rg] = 0.f;

  auto stage = [&](int c, int kb) {
    const u16* Ab;
    int Astr, kOff;
    if (kb < kSplit) { Ab = A1; Astr = s1; kOff = kb; }
    else { Ab = A2; Astr = 512; kOff = kb - kSplit; }
    async16(Ab + (size_t)(mBase + r) * Astr + kOff + c8, As[c] + r * 32 + c8);
    async16(Ab + (size_t)(mBase + r + 64) * Astr + kOff + c8,
            As[c] + (r + 64) * 32 + c8);
    async16(Bt + (size_t)(nBase + r) * 576 + kb + c8, Bs[c] + r * 32 + c8);
    async16(Bt + (size_t)(nBase + r + 64) * 576 + kb + c8,
            Bs[c] + (r + 64) * 32 + c8);
  };

  stage(0, 0);
  __syncthreads();
  int cur = 0;
  for (int kb = 0; kb < K; kb += 32) {
    if (kb + 32 < K) stage(cur ^ 1, kb + 32);
    bf16x8 av[4], bv[4];
#pragma unroll
    for (int i = 0; i < 4; i++)
      av[i] = *(const bf16x8*)(As[cur] + (wm * 64 + i * 16 + l15) * 32 + q8);
#pragma unroll
    for (int j = 0; j < 4; j++)
      bv[j] = *(const bf16x8*)(Bs[cur] + (wn * 64 + j * 16 + l15) * 32 + q8);
#pragma unroll
    for (int i = 0; i < 4; i++)
#pragma unroll
      for (int j = 0; j < 4; j++)
        acc[i][j] = __builtin_amdgcn_mfma_f32_16x16x32_bf16(av[i], bv[j],
                                                            acc[i][j], 0, 0, 0);
    __syncthreads();
    cur ^= 1;
  }

  if (EPI == 2) {
#pragma unroll
    for (int m = 0; m < 2; m++) {
      int mol = (mBase + wm * 64 + m * 32) >> 5;
      float inv_le = 1.0f / (float)scope[mol * 2 + 1];
#pragma unroll
      for (int j = 0; j < 4; j++) {
        int col = nBase + wn * 64 + j * 16 + l15;
        float bias = bo[col];
        float s = 0.f;
#pragma unroll
        for (int i = 2 * m; i < 2 * m + 2; i++)
#pragma unroll
          for (int rg = 0; rg < 4; rg++)
            s += fmaxf(acc[i][j][rg] + bias, 0.f);
        s += __shfl_xor(s, 16, 64);
        s += __shfl_xor(s, 32, 64);
        if (lane < 16) out[(size_t)mol * HID + col] = s * inv_le;
      }
    }
  } else {
#pragma unroll
    for (int i = 0; i < 4; i++) {
      int row = mBase + wm * 64 + i * 16 + (lane >> 4) * 4;
#pragma unroll
      for (int j = 0; j < 4; j++) {
        int col = nBase + wn * 64 + j * 16 + l15;
#pragma unroll
        for (int rg = 0; rg < 4; rg++) {
          size_t gi = (size_t)(row + rg) * HID + col;
          gw[gi] = f2bf(fmaxf(acc[i][j][rg], 0.f));
        }
      }
    }
  }
}

// ---------------- MIXED: gemm tiles [0,c1) || gather chunks [c1,CH) ---------
// 512 threads. Role by blockIdx only -> no divergent barriers, no waits.
// PHASE 0 (bond iter): gemm EPI0 (A=[fbc|nei], B=wcat, writes gw parity);
//                      gather bonds reads tab(parity) writes nei.
// PHASE 1 (atoms): gemm EPI2 (A=ainput str576, B=wo_t, writes out);
//                  gather atoms writes ainput (+fatoms tail).
template <int PHASE>
__global__ __launch_bounds__(512, 4) void mixed(
    const u16* __restrict__ tab, u32 pOff, u16* __restrict__ gw,
    u16* __restrict__ nei, const u16* __restrict__ fbc,
    const u16* __restrict__ W, const int* __restrict__ graph,
    const float* __restrict__ fatoms, const float* __restrict__ bo,
    const int* __restrict__ scope, float* __restrict__ out, int nGemmBlk,
    int chunkStart) {
  __shared__ __align__(16) u16 As[2][128 * 32];
  __shared__ __align__(16) u16 Bs[2][128 * 32];
  constexpr int MTX = PHASE ? 32 : 64;              // per-XCD m-tiles
  constexpr int ROWQ = PHASE ? (NA / 8) : (NB / 8); // per-XCD rows
  const int xcd = blockIdx.x & 7;
  const int u = blockIdx.x >> 3;
  const int t = threadIdx.x;
  const int lane = t & 63;

  if (u < nGemmBlk) {  // ================= gemm role =================
    const int tile = u >> 2, nb = u & 3;
    const int mBase = (xcd * MTX + tile) * 128;
    const int nBase = nb * 128;
    const int w = t >> 6;
    const int wm = w & 1, wn = w >> 1;  // wn in [0,4): 32-col strip
    const int r = t >> 2;               // [0,128)
    const int c8 = (t & 3) * 8;
    const int q8 = (lane >> 4) * 8;
    const int l15 = lane & 15;
    const int K = 576;

    f32x4 acc[4][2];
#pragma unroll
    for (int i = 0; i < 4; i++)
#pragma unroll
      for (int j = 0; j < 2; j++)
#pragma unroll
        for (int rg = 0; rg < 4; rg++) acc[i][j][rg] = 0.f;

    auto stage = [&](int c, int kb) {
      const u16* Ab;
      int Astr, kOff;
      if (PHASE == 0) {
        if (kb < 64) { Ab = fbc; Astr = 40; kOff = kb; }
        else { Ab = nei; Astr = 512; kOff = kb - 64; }
      } else {
        Ab = nei; Astr = 576; kOff = kb;  // ainput
      }
      async16(Ab + (size_t)(mBase + r) * Astr + kOff + c8, As[c] + r * 32 + c8);
      async16(W + (size_t)(nBase + r) * 576 + kb + c8, Bs[c] + r * 32 + c8);
    };

    stage(0, 0);
    __syncthreads();
    int cur = 0;
    for (int kb = 0; kb < K; kb += 32) {
      if (kb + 32 < K) stage(cur ^ 1, kb + 32);
      bf16x8 av[4], bv[2];
#pragma unroll
      for (int i = 0; i < 4; i++)
        av[i] = *(const bf16x8*)(As[cur] + (wm * 64 + i * 16 + l15) * 32 + q8);
#pragma unroll
      for (int j = 0; j < 2; j++)
        bv[j] = *(const bf16x8*)(Bs[cur] + (wn * 32 + j * 16 + l15) * 32 + q8);
#pragma unroll
      for (int i = 0; i < 4; i++)
#pragma unroll
        for (int j = 0; j < 2; j++)
          acc[i][j] = __builtin_amdgcn_mfma_f32_16x16x32_bf16(av[i], bv[j],
                                                              acc[i][j], 0, 0, 0);
      __syncthreads();
      cur ^= 1;
    }

    if (PHASE == 1) {
#pragma unroll
      for (int m = 0; m < 2; m++) {
        int mol = (mBase + wm * 64 + m * 32) >> 5;
        float inv_le = 1.0f / (float)scope[mol * 2 + 1];
#pragma unroll
        for (int j = 0; j < 2; j++) {
          int col = nBase + wn * 32 + j * 16 + l15;
          float bias = bo[col];
          float s = 0.f;
#pragma unroll
          for (int i = 2 * m; i < 2 * m + 2; i++)
#pragma unroll
            for (int rg = 0; rg < 4; rg++)
              s += fmaxf(acc[i][j][rg] + bias, 0.f);
          s += __shfl_xor(s, 16, 64);
          s += __shfl_xor(s, 32, 64);
          if (lane < 16) out[(size_t)mol * HID + col] = s * inv_le;
        }
      }
    } else {
#pragma unroll
      for (int i = 0; i < 4; i++) {
        int row = mBase + wm * 64 + i * 16 + (lane >> 4) * 4;
#pragma unroll
        for (int j = 0; j < 2; j++) {
          int col = nBase + wn * 32 + j * 16 + l15;
#pragma unroll
          for (int rg = 0; rg < 4; rg++) {
            size_t gi = (size_t)(row + rg) * HID + col;
            gw[gi] = f2bf(fmaxf(acc[i][j][rg], 0.f));
          }
        }
      }
    }
  } else {  // ================= gather role =================
    const int g = u - nGemmBlk;  // 8 rows per block (8 waves)
    const int w = t >> 6;
    const int row = xcd * ROWQ + chunkStart * 128 + g * 8 + w;
    const int* idxp = graph + row * MAX_NB;
    float acc[8] = {0, 0, 0, 0, 0, 0, 0, 0};
#pragma unroll
    for (int j = 0; j < MAX_NB; j++) {
      int id = idxp[j];
      u32 off = (u32)id * HID + (id >= NMESS ? pOff : 0u);
      uint4 v = *(const uint4*)(tab + (size_t)off + lane * 8);
      acc[0] += bflo(v.x); acc[1] += bfhi(v.x);
      acc[2] += bflo(v.y); acc[3] += bfhi(v.y);
      acc[4] += bflo(v.z); acc[5] += bfhi(v.z);
      acc[6] += bflo(v.w); acc[7] += bfhi(v.w);
    }
    uint4 o;
    o.x = (u32)f2bf(acc[0]) | ((u32)f2bf(acc[1]) << 16);
    o.y = (u32)f2bf(acc[2]) | ((u32)f2bf(acc[3]) << 16);
    o.z = (u32)f2bf(acc[4]) | ((u32)f2bf(acc[5]) << 16);
    o.w = (u32)f2bf(acc[6]) | ((u32)f2bf(acc[7]) << 16);
    if (PHASE == 1) {
      u16* arow = nei + (size_t)row * 576;
      *(uint4*)(arow + lane * 8) = o;
      float tv = (lane < 35) ? fatoms[(size_t)row * 35 + lane] : 0.f;
      arow[512 + lane] = f2bf(tv);
    } else {
      *(uint4*)(nei + (size_t)row * HID + lane * 8) = o;
    }
  }
}

// ---------------- launch ----------------
extern "C" void kernel_launch(void* const* d_in, const int* in_sizes, int n_in,
                              void* d_out, int out_size, void* d_ws,
                              size_t ws_size, hipStream_t stream) {
  const float* fatoms = (const float*)d_in[0];
  const float* fbonds = (const float*)d_in[1];
  const int* agraph = (const int*)d_in[2];
  const int* bgraph = (const int*)d_in[3];
  const int* scope = (const int*)d_in[4];
  const float* tree = (const float*)d_in[5];
  const float* Wi = (const float*)d_in[6];
  const float* Wh = (const float*)d_in[7];
  const float* Wo = (const float*)d_in[8];
  const float* bo = (const float*)d_in[9];
  float* out = (float*)d_out;

  // overlap: [tab 8.39][graphA 67.1][graphB 67.1][nei 67.1][fbc 5.24]
  //          [wcat .59][wo_t .59] = 216,137,792 B
  // serial (drop graphB) = 149,028,928 B
  const int ov = ws_size >= 216137792ull;
  u16* tab = (u16*)d_ws;
  u16* graphA = tab + (size_t)NMESS * HID;
  u16* nei = graphA + (size_t)(ov ? 2 : 1) * GAPE;
  u16* fbc = nei + (size_t)GAPE;
  u16* wcat = fbc + ((size_t)NB * 40 + 32);
  u16* wo_t = wcat + 576 * 512;

  const int prepTot = NMESS * HID + NB * 40 + 32 + 2 * 576 * 512;
  prep_kernel<<<(prepTot + 255) / 256, 256, 0, stream>>>(fbonds, tree, Wi, Wh,
                                                         Wo, tab, fbc, wcat,
                                                         wo_t);

  // init: graphA = relu(fbonds @ Wi), K=64 (wcat rows 40..63 are zero)
  gemm_k<0><<<2048, 256, 0, stream>>>(fbc, 40, 64, nullptr, wcat, 64, 64, 0,
                                      graphA, nullptr, nullptr, nullptr);

  if (ov) {
    const int C1 = 45;  // bond split: gather 45/64 pure, 19/64 mixed
    const int CA = 22;  // atom split: 22/32 pure, 10/32 mixed
    for (int d = 0; d < 5; d++) {
      u32 pOff = (u32)(d & 1) * GAPE;
      u16* gw = graphA + (size_t)((d + 1) & 1) * GAPE;
      gather_bonds<<<8 * C1 * 32, 256, 0, stream>>>(tab, bgraph, nei, pOff);
      mixed<0><<<8 * (C1 * 4 + (64 - C1) * 16), 512, 0, stream>>>(
          tab, pOff, gw, nei, fbc, wcat, bgraph, nullptr, nullptr, nullptr,
          nullptr, C1 * 4, C1);
      gemm_k<0><<<8 * (64 - C1) * 4, 256, 0, stream>>>(
          fbc, 40, 64, nei, wcat, 576, 64, C1, gw, nullptr, nullptr, nullptr);
    }
    // atoms read parity 1 (iter d=4 wrote (4+1)&1 = 1)
    gather_atoms<<<8 * CA * 32, 256, 0, stream>>>(tab, agraph, fatoms, nei,
                                                  GAPE);
    mixed<1><<<8 * (CA * 4 + (32 - CA) * 16), 512, 0, stream>>>(
        tab, GAPE, nullptr, nei, nullptr, wo_t, agraph, fatoms, bo, scope, out,
        CA * 4, CA);
    gemm_k<2><<<8 * (32 - CA) * 4, 256, 0, stream>>>(
        nei, 576, 576, nullptr, wo_t, 576, 32, CA, nullptr, bo, scope, out);
  } else {
    for (int d = 0; d < 5; d++) {
      gather_bonds<<<NB / 4, 256, 0, stream>>>(tab, bgraph, nei, 0u);
      gemm_k<0><<<2048, 256, 0, stream>>>(fbc, 40, 64, nei, wcat, 576, 64, 0,
                                          graphA, nullptr, nullptr, nullptr);
    }
    gather_atoms<<<NA / 4, 256, 0, stream>>>(tab, agraph, fatoms, nei, 0u);
    gemm_k<2><<<1024, 256, 0, stream>>>(nei, 576, 576, nullptr, wo_t, 576, 32,
                                        0, nullptr, bo, scope, out);
  }
}